// Round 8
// baseline (828.142 us; speedup 1.0000x reference)
//
#include <hip/hip_runtime.h>

// ---------------------------------------------------------------------------
// Self-attention (B=4, S=4096, D=1024), fp32 in/out.
// Q/K chain all-int8 fixed point:
//   X=(x1+x2/256)/16, W=(w1+w2/256)/256  -> proj: 4-term i8 MFMA, 3 exact
//   i32 accs, Q=(a1+a2/256+a3/65536)/4096, requantized to dual-i8 (1/16).
//   QK^T: 3-term i8 MFMA (dropped ql*kl ~0.01 logit sigma, verified R7).
// V / PV single-bf16. Logit noise budget ~0.013 << 0.1 flip threshold.
// R8: projections i8 (Q 117->~75us; 4th term ~free: proj tile is ds-bound);
// qk tile 128x128 (flips ds-bound->MFMA-bound). sc aliases dead Xq region.
// ---------------------------------------------------------------------------

typedef __attribute__((ext_vector_type(4))) float floatx4;
typedef __attribute__((ext_vector_type(4))) int intx4;
typedef __attribute__((ext_vector_type(8))) short shortx8;
typedef unsigned short ushort_t;

__device__ __forceinline__ ushort_t f2bf(float f) {
  union { float f; unsigned u; } x; x.f = f;
  unsigned r = x.u + 0x7fffu + ((x.u >> 16) & 1u);  // RNE
  return (ushort_t)(r >> 16);
}
__device__ __forceinline__ float bf2f(ushort_t h) {
  union { unsigned u; float f; } x; x.u = ((unsigned)h) << 16; return x.f;
}
// dual-int8 quant at scale s: v ~= (q1 + q2/256)/s
__device__ __forceinline__ void quant8s(float v, float s, char& q1, char& q2) {
  float vs = v * s;
  float h = rintf(vs);
  h = fminf(fmaxf(h, -127.f), 127.f);
  float l = rintf((vs - h) * 256.0f);
  l = fminf(fmaxf(l, -127.f), 127.f);
  q1 = (char)(int)h; q2 = (char)(int)l;
}

// Async global->LDS, 16B/lane (m97 lever). LDS dest = wave-uniform base +
// lane*16 (m104/m108); lane->LDS mapping contiguous in lane order.
__device__ __forceinline__ void gload_lds16(const void* g, void* l) {
  __builtin_amdgcn_global_load_lds(
      (__attribute__((address_space(1))) void*)(uintptr_t)g,
      (__attribute__((address_space(3))) void*)(unsigned)(uintptr_t)l,
      16, 0, 0);
}

// ---------------- dual-int8 GEMM: C ~= A * B^T -----------------------------
// A,B dual-i8 streams [*,K] stride K. NACC=2: acc1=a1b1, acc2=a1b2+a2b1.
// NACC=3: + acc3=a2b2.  v = (a1 + a2/256 [+ a3/65536]) * oscale.
// OMODE: 0 = C fp32 [row*ldc+col]; 1 = C dual-i8 via quant8s(v,16).
// LMODE: 0 none; 1 skip block if col0>=sent (QK^T);
//        3 skip block if (row0&4095)>=roundup(sent(row0>>12),128) (K proj)
template<int TM, int TN, int NACC, int OMODE, int LMODE>
__global__ __launch_bounds__(256)
void gemm_i8(const char* __restrict__ A0g, const char* __restrict__ A1g,
             const char* __restrict__ B0g, const char* __restrict__ B1g,
             void* __restrict__ C0v, void* __restrict__ C1v,
             int K, int ldc, float oscale, const int* __restrict__ lenp, int b)
{
  constexpr int BM = TM * 32, BN = TN * 32;
  __shared__ char As[2][BM][64];
  __shared__ char Bs[2][BN][64];
  const int tid = threadIdx.x;
  const long row0 = (long)blockIdx.x * BM;
  const long col0 = (long)blockIdx.y * BN;

  if constexpr (LMODE == 1) {
    const int sent = lenp[b] * 2;
    if (col0 >= sent) return;
  } else if constexpr (LMODE == 3) {
    const int sent = lenp[row0 >> 12] * 2;
    if ((int)(row0 & 4095) >= ((sent + 127) & ~127)) return;
  }

  const int sr = tid >> 2, sc16 = (tid & 3) * 16;
  const char* pA0 = A0g + (row0 + sr) * (long)K + sc16;
  const char* pA1 = A1g + (row0 + sr) * (long)K + sc16;
  const char* pB0 = B0g + (col0 + sr) * (long)K + sc16;
  const char* pB1 = B1g + (col0 + sr) * (long)K + sc16;
  char* lA0 = &As[0][sr][sc16];
  char* lA1 = &As[1][sr][sc16];
  char* lB0 = &Bs[0][sr][sc16];
  char* lB1 = &Bs[1][sr][sc16];
  const long jstr = 64 * (long)K;

  const int wid = tid >> 6, lane = tid & 63;
  const int wm = (wid >> 1) * (BM / 2), wn = (wid & 1) * (BN / 2);
  const int lr = lane & 15, lq = lane >> 4;

  intx4 acc1[TM][TN] = {};
  intx4 acc2[TM][TN] = {};
  intx4 acc3[NACC == 3 ? TM : 1][NACC == 3 ? TN : 1] = {};

  for (int k0 = 0; k0 < K; k0 += 64) {
#pragma unroll
    for (int j = 0; j < TM / 2; ++j) {
      gload_lds16(pA0 + k0 + j * jstr, lA0 + j * 4096);
      gload_lds16(pA1 + k0 + j * jstr, lA1 + j * 4096);
    }
#pragma unroll
    for (int j = 0; j < TN / 2; ++j) {
      gload_lds16(pB0 + k0 + j * jstr, lB0 + j * 4096);
      gload_lds16(pB1 + k0 + j * jstr, lB1 + j * 4096);
    }
    __syncthreads();

    intx4 ah[TM], al[TM], bh[TN], bl[TN];
#pragma unroll
    for (int t = 0; t < TM; ++t) {
      ah[t] = *(const intx4*)&As[0][wm + t * 16 + lr][lq * 16];
      al[t] = *(const intx4*)&As[1][wm + t * 16 + lr][lq * 16];
    }
#pragma unroll
    for (int t = 0; t < TN; ++t) {
      bh[t] = *(const intx4*)&Bs[0][wn + t * 16 + lr][lq * 16];
      bl[t] = *(const intx4*)&Bs[1][wn + t * 16 + lr][lq * 16];
    }
#pragma unroll
    for (int mt = 0; mt < TM; ++mt)
#pragma unroll
      for (int nt = 0; nt < TN; ++nt) {
        acc1[mt][nt] = __builtin_amdgcn_mfma_i32_16x16x64_i8(ah[mt], bh[nt], acc1[mt][nt], 0, 0, 0);
        acc2[mt][nt] = __builtin_amdgcn_mfma_i32_16x16x64_i8(ah[mt], bl[nt], acc2[mt][nt], 0, 0, 0);
        acc2[mt][nt] = __builtin_amdgcn_mfma_i32_16x16x64_i8(al[mt], bh[nt], acc2[mt][nt], 0, 0, 0);
        if constexpr (NACC == 3)
          acc3[mt][nt] = __builtin_amdgcn_mfma_i32_16x16x64_i8(al[mt], bl[nt], acc3[mt][nt], 0, 0, 0);
      }
    __syncthreads();
  }

  // C/D layout (m89/m91): col = lane&15, row = (lane>>4)*4 + reg
#pragma unroll
  for (int mt = 0; mt < TM; ++mt)
#pragma unroll
    for (int nt = 0; nt < TN; ++nt) {
      long col = col0 + wn + nt * 16 + lr;
#pragma unroll
      for (int r = 0; r < 4; ++r) {
        long row = row0 + wm + mt * 16 + lq * 4 + r;
        float v = (float)acc1[mt][nt][r] + (float)acc2[mt][nt][r] * (1.0f / 256.0f);
        if constexpr (NACC == 3)
          v += (float)acc3[mt][nt][r] * (1.0f / 65536.0f);
        v *= oscale;
        if constexpr (OMODE == 0) {
          ((float*)C0v)[row * ldc + col] = v;
        } else {
          char q1, q2;
          quant8s(v, 16.0f, q1, q2);
          ((char*)C0v)[row * ldc + col] = q1;
          ((char*)C1v)[row * ldc + col] = q2;
        }
      }
    }
}

// ---------------- bf16 GEMM (V proj / PV): C = A * B^T ---------------------
// OMODE: 0 = C fp32 [row*ldc+col]; 2 = C bf16 per-batch transposed.
// LMODE: 2 kend=roundup(sent(b0),128) (PV); 3 row-skip (V proj)
template<int TM, int TN, int OMODE, int LMODE>
__global__ __launch_bounds__(256)
void gemm_bt(const ushort_t* __restrict__ A0g, const ushort_t* __restrict__ B0g,
             void* __restrict__ C0v, int K, int lda, int ldc, long bstride,
             const int* __restrict__ lenp, int b0)
{
  constexpr int BM = TM * 32, BN = TN * 32;
  __shared__ ushort_t As[BM][32];
  __shared__ ushort_t Bs[BN][32];
  const int tid = threadIdx.x;
  const long row0 = (long)blockIdx.x * BM;
  const long col0 = (long)blockIdx.y * BN;

  int kend = K;
  if constexpr (LMODE == 2) {
    const int sent = lenp[b0] * 2;
    kend = (sent + 127) & ~127;
  } else if constexpr (LMODE == 3) {
    const int sent = lenp[row0 >> 12] * 2;
    if ((int)(row0 & 4095) >= ((sent + 127) & ~127)) return;
  }

  const int sr = tid >> 2, scol = (tid & 3) * 8;
  const ushort_t* pA0 = A0g + (row0 + sr) * (long)lda + scol;
  const ushort_t* pB0 = B0g + (col0 + sr) * (long)K + scol;
  ushort_t* lA0 = &As[sr][scol];
  ushort_t* lB0 = &Bs[sr][scol];
  const long jA = 64 * (long)lda, jB = 64 * (long)K;

  const int wid = tid >> 6, lane = tid & 63;
  const int wm = (wid >> 1) * (BM / 2), wn = (wid & 1) * (BN / 2);
  const int lr = lane & 15, lq = lane >> 4;

  floatx4 acc[TM][TN] = {};

  for (int k0 = 0; k0 < kend; k0 += 32) {
#pragma unroll
    for (int j = 0; j < TM / 2; ++j) gload_lds16(pA0 + k0 + j * jA, lA0 + j * 2048);
#pragma unroll
    for (int j = 0; j < TN / 2; ++j) gload_lds16(pB0 + k0 + j * jB, lB0 + j * 2048);
    __syncthreads();

    shortx8 ah[TM], bh[TN];
#pragma unroll
    for (int t = 0; t < TM; ++t) ah[t] = *(const shortx8*)&As[wm + t * 16 + lr][lq * 8];
#pragma unroll
    for (int t = 0; t < TN; ++t) bh[t] = *(const shortx8*)&Bs[wn + t * 16 + lr][lq * 8];
#pragma unroll
    for (int mt = 0; mt < TM; ++mt)
#pragma unroll
      for (int nt = 0; nt < TN; ++nt)
        acc[mt][nt] = __builtin_amdgcn_mfma_f32_16x16x32_bf16(ah[mt], bh[nt], acc[mt][nt], 0, 0, 0);
    __syncthreads();
  }

#pragma unroll
  for (int mt = 0; mt < TM; ++mt)
#pragma unroll
    for (int nt = 0; nt < TN; ++nt) {
      long col = col0 + wn + nt * 16 + lr;
      if constexpr (OMODE == 2) {
        long row = row0 + wm + mt * 16 + lq * 4;
        long bb = row >> 12, s = row & 4095;
        ushort4 pk;
        pk.x = f2bf(acc[mt][nt][0]); pk.y = f2bf(acc[mt][nt][1]);
        pk.z = f2bf(acc[mt][nt][2]); pk.w = f2bf(acc[mt][nt][3]);
        *(ushort4*)&((ushort_t*)C0v)[bb * bstride + col * ldc + s] = pk;
      } else {
#pragma unroll
        for (int r = 0; r < 4; ++r) {
          long row = row0 + wm + mt * 16 + lq * 4 + r;
          ((float*)C0v)[row * ldc + col] = acc[mt][nt][r];
        }
      }
    }
}

// X -> dual-i8 (scale 16) + bf16 hi, one pass.
__global__ __launch_bounds__(256)
void cast_x(const float* __restrict__ in, char* __restrict__ q1,
            char* __restrict__ q2, ushort_t* __restrict__ hi, int n4) {
  int i = blockIdx.x * 256 + threadIdx.x;
  if (i >= n4) return;
  float4 v = ((const float4*)in)[i];
  char4 a, b; ushort4 h;
  quant8s(v.x, 16.0f, a.x, b.x); h.x = f2bf(v.x);
  quant8s(v.y, 16.0f, a.y, b.y); h.y = f2bf(v.y);
  quant8s(v.z, 16.0f, a.z, b.z); h.z = f2bf(v.z);
  quant8s(v.w, 16.0f, a.w, b.w); h.w = f2bf(v.w);
  ((char4*)q1)[i] = a; ((char4*)q2)[i] = b; ((ushort4*)hi)[i] = h;
}

// Weights: y=0 Wq, y=1 Wk -> dual-i8 (scale 256); y=2 Wv -> bf16 hi/lo pair.
__global__ __launch_bounds__(256)
void cast_w(const float* __restrict__ wq, const float* __restrict__ wk,
            const float* __restrict__ wv, char* __restrict__ q1a,
            char* __restrict__ q2a, char* __restrict__ q1b,
            char* __restrict__ q2b, ushort_t* __restrict__ vh,
            ushort_t* __restrict__ vl, int n4) {
  int i = blockIdx.x * 256 + threadIdx.x;
  if (i >= n4) return;
  if (blockIdx.y == 2) {
    float4 v = ((const float4*)wv)[i];
    ushort4 h, l;
    h.x = f2bf(v.x); l.x = f2bf(v.x - bf2f(h.x));
    h.y = f2bf(v.y); l.y = f2bf(v.y - bf2f(h.y));
    h.z = f2bf(v.z); l.z = f2bf(v.z - bf2f(h.z));
    h.w = f2bf(v.w); l.w = f2bf(v.w - bf2f(h.w));
    ((ushort4*)vh)[i] = h; ((ushort4*)vl)[i] = l;
  } else {
    const float* in = (blockIdx.y == 0) ? wq : wk;
    char* p1 = (blockIdx.y == 0) ? q1a : q1b;
    char* p2 = (blockIdx.y == 0) ? q2a : q2b;
    float4 v = ((const float4*)in)[i];
    char4 a, b;
    quant8s(v.x, 256.0f, a.x, b.x);
    quant8s(v.y, 256.0f, a.y, b.y);
    quant8s(v.z, 256.0f, a.z, b.z);
    quant8s(v.w, 256.0f, a.w, b.w);
    ((char4*)p1)[i] = a; ((char4*)p2)[i] = b;
  }
}

// Masked softmax; reads fp32 row, writes bf16 P into the first half in place.
__global__ __launch_bounds__(256)
void softmax_rows(float* __restrict__ scores, const int* __restrict__ length, int b0) {
  const long row = blockIdx.x;
  float* p = scores + row * 4096;
  const int sent = length[b0] * 2;
  const int sentceil = (sent + 127) & ~127;
  const int tid = threadIdx.x;
  float vals[16];
  float mx = -3.4e38f;
  int nj = 0;
  for (int c = tid; c < sentceil; c += 256) {
    float v = p[c];
    v = (c < sent) ? v : -2147483648.0f;   // NEG_BIG
    vals[nj++] = v;
    mx = fmaxf(mx, v);
  }
#pragma unroll
  for (int off = 32; off > 0; off >>= 1) mx = fmaxf(mx, __shfl_down(mx, off));
  __shared__ float red[8];
  if ((tid & 63) == 0) red[tid >> 6] = mx;
  __syncthreads();
  mx = fmaxf(fmaxf(red[0], red[1]), fmaxf(red[2], red[3]));
  float sum = 0.f;
  for (int j = 0; j < nj; ++j) { vals[j] = __expf(vals[j] - mx); sum += vals[j]; }
#pragma unroll
  for (int off = 32; off > 0; off >>= 1) sum += __shfl_down(sum, off);
  __syncthreads();
  if ((tid & 63) == 0) red[tid >> 6] = sum;
  __syncthreads();
  float inv = 1.0f / (red[0] + red[1] + red[2] + red[3]);
  ushort_t* pb = (ushort_t*)p;
  int j = 0;
  for (int c = tid; c < sentceil; c += 256) pb[c] = f2bf(vals[j++] * inv);
}

extern "C" void kernel_launch(void* const* d_in, const int* in_sizes, int n_in,
                              void* d_out, int out_size, void* d_ws, size_t ws_size,
                              hipStream_t stream) {
  const float* X   = (const float*)d_in[0];
  const int*   len = (const int*)d_in[1];
  const float* Wq  = (const float*)d_in[2];
  const float* Wk  = (const float*)d_in[3];
  const float* Wv  = (const float*)d_in[4];
  float* out = (float*)d_out;

  const int Bn = 4, S = 4096, D = 1024;
  const long MS = (long)Bn * S;

  char* w = (char*)d_ws;
  float* sc = (float*)w;               // 64 MB score region (per-batch reuse)
  char* Xq1 = w;                       // aliases sc: dead before first QK^T
  char* Xq2 = w + MS * D;              // 16.8 + 16.8 MB < 64 MB
  w += (long)S * S * 4;
  char* Qh8 = w; w += MS * D;
  char* Ql8 = w; w += MS * D;
  char* Kh8 = w; w += MS * D;
  char* Kl8 = w; w += MS * D;
  ushort_t* Vt  = (ushort_t*)w; w += MS * D * 2;   // bf16 [B][D][S]
  ushort_t* Xhi = (ushort_t*)w; w += MS * D * 2;   // bf16 X (V proj only)
  char* Wq1 = w; w += (long)D * D;
  char* Wq2 = w; w += (long)D * D;
  char* Wk1 = w; w += (long)D * D;
  char* Wk2 = w; w += (long)D * D;
  ushort_t* Wvh = (ushort_t*)w; w += (long)D * D * 2;
  ushort_t* Wvl = (ushort_t*)w; w += (long)D * D * 2;   // ~207 MB total

  const int n4x = (int)(MS * D / 4), n4w = D * D / 4;
  cast_x<<<(n4x + 255) / 256, 256, 0, stream>>>(X, Xq1, Xq2, Xhi, n4x);
  cast_w<<<dim3((n4w + 255) / 256, 3), 256, 0, stream>>>(
      Wq, Wk, Wv, Wq1, Wq2, Wk1, Wk2, Wvh, Wvl, n4w);

  dim3 blk(256);
  // Q proj: i8 4-term, 128x64 tile, out dual-i8; oscale = 2^-12
  gemm_i8<4, 2, 3, 1, 0><<<dim3(MS / 128, D / 64), blk, 0, stream>>>(
      Xq1, Xq2, Wq1, Wq2, Qh8, Ql8, D, D, 1.0f / 4096.0f, len, 0);
  // K proj: same + row-skip
  gemm_i8<4, 2, 3, 1, 3><<<dim3(MS / 128, D / 64), blk, 0, stream>>>(
      Xq1, Xq2, Wk1, Wk2, Kh8, Kl8, D, D, 1.0f / 4096.0f, len, 0);
  // V proj: bf16 single, transposed per batch, row-skip
  gemm_bt<4, 4, 2, 3><<<dim3(MS / 128, D / 128), blk, 0, stream>>>(
      Xhi, Wvh, Vt, D, D, S, (long)D * S, len, 0);

  for (int b = 0; b < Bn; ++b) {
    const long so = (long)b * S * D;
    // QK^T: i8 3-term, 128x128 tile, fp32 scores; oscale = 2^-8
    gemm_i8<4, 4, 2, 0, 1><<<dim3(S / 128, S / 128), blk, 0, stream>>>(
        Qh8 + so, Ql8 + so, Kh8 + so, Kl8 + so, sc, nullptr, D, S,
        1.0f / 256.0f, len, b);
    softmax_rows<<<S, 256, 0, stream>>>(sc, len, b);
    // PV: P bf16 (in-place rows, stride 2S), Vt single bf16, kend by length
    gemm_bt<4, 2, 0, 2><<<dim3(S / 128, D / 64), blk, 0, stream>>>(
        (const ushort_t*)sc, Vt + (long)b * D * S, out + so, S, 2 * S, D, 0,
        len, b);
  }
}